// Round 1
// 828.625 us; speedup vs baseline: 1.2385x; 1.2385x over previous
//
#include <hip/hip_runtime.h>
#include <stdint.h>

#define NG   8
#define BT   4096
#define DIN  1024
#define DHID 2048
#define DOUT 1024

typedef __bf16 bf16x8 __attribute__((ext_vector_type(8)));
typedef float  f32x4  __attribute__((ext_vector_type(4)));

__device__ __forceinline__ unsigned short f2bf(float f) {
    union { float f; unsigned u; } v; v.f = f;
    // round-to-nearest-even fp32 -> bf16 (kept identical to previous kernel for bit-identical numerics)
    return (unsigned short)((v.u + 0x7fffu + ((v.u >> 16) & 1u)) >> 16);
}

// async 16B global -> LDS (DMA, no VGPR round-trip). LDS dest is wave-uniform
// base; HW adds lane*16. Global src address is per-lane (enables swizzle).
__device__ __forceinline__ void async16(const unsigned short* g, unsigned short* l) {
    __builtin_amdgcn_global_load_lds((const __attribute__((address_space(1))) void*)g,
                                     (__attribute__((address_space(3))) void*)l,
                                     16, 0, 0);
}

// ---------------- prepass 1: x (fp32, token-interleaved) -> xb[gl][b][k] bf16 ----------------
__global__ __launch_bounds__(256)
void k_cvt_x(const float* __restrict__ x, unsigned short* __restrict__ xb,
             int g0, int ngl) {
    size_t total = (size_t)ngl * BT * (DIN / 4);
    size_t stride = (size_t)gridDim.x * blockDim.x;
    for (size_t i = (size_t)blockIdx.x * blockDim.x + threadIdx.x; i < total; i += stride) {
        size_t e = i * 4;
        int k  = (int)(e & (DIN - 1));
        size_t rb = e >> 10;                  // / DIN
        int b  = (int)(rb & (BT - 1));
        int gl = (int)(rb >> 12);             // / BT
        const float4 v = *(const float4*)(x + ((size_t)b * NG + (g0 + gl)) * DIN + k);
        ushort4 h;
        h.x = f2bf(v.x); h.y = f2bf(v.y); h.z = f2bf(v.z); h.w = f2bf(v.w);
        *(ushort4*)(xb + e) = h;
    }
}

// ---------------- prepass 2: weight [g][K][N] fp32 -> [gl][N][K] bf16 (transpose+convert) ----------------
__global__ __launch_bounds__(256)
void k_cvt_wT(const float* __restrict__ w, unsigned short* __restrict__ wt,
              int K, int N, int g0) {
    __shared__ unsigned short ts[64][72];   // [n][k], 144B rows (16B aligned)
    int nt = blockIdx.x;      // tile along N
    int kt = blockIdx.y;      // tile along K
    int gl = blockIdx.z;
    const float* src = w + ((size_t)(g0 + gl) * K + kt * 64) * N + nt * 64;
    unsigned short* dst = wt + ((size_t)gl * N + nt * 64) * K + kt * 64;
    int tid = threadIdx.x;
    int c4 = (tid & 15) * 4;    // n within tile
    int r0 = tid >> 4;          // k row base
    #pragma unroll
    for (int i = 0; i < 4; i++) {
        int r = r0 + i * 16;
        float4 v = *(const float4*)(src + (size_t)r * N + c4);
        ts[c4 + 0][r] = f2bf(v.x);
        ts[c4 + 1][r] = f2bf(v.y);
        ts[c4 + 2][r] = f2bf(v.z);
        ts[c4 + 3][r] = f2bf(v.w);
    }
    __syncthreads();
    int kc = (tid & 7) * 8;
    int n0 = tid >> 3;          // 0..31
    #pragma unroll
    for (int i = 0; i < 2; i++) {
        int n = n0 + i * 32;
        uint4 v = *(const uint4*)&ts[n][kc];
        *(uint4*)(dst + (size_t)n * K + kc) = v;
    }
}

// -------- GEMM 1: hid[gl][b][h] = silu(x@Wg) * (x@Wu), all-bf16, gload_lds staging --------
__global__ __launch_bounds__(256, 2)
void k_gateup(const unsigned short* __restrict__ xb,
              const unsigned short* __restrict__ wgb,
              const unsigned short* __restrict__ wub,
              unsigned short* __restrict__ hid) {
    const int HT = DHID / 128;   // 16
    const int MT = BT / 128;     // 32
    int bid = blockIdx.x;
    int ht = bid % HT;
    int mt = (bid / HT) % MT;
    int gl = bid / (HT * MT);

    __shared__ unsigned short As[128 * 64];  // linear [row][64k], chunk-swizzled contents
    __shared__ unsigned short Bg[128 * 64];
    __shared__ unsigned short Bu[128 * 64];

    int tid = threadIdx.x;
    int lane = tid & 63, wave = tid >> 6;
    int quad = lane >> 4, l16 = lane & 15;
    int wm = (wave >> 1) * 64, wn = (wave & 1) * 64;

    f32x4 ag[4][4], au[4][4];
    #pragma unroll
    for (int i = 0; i < 4; i++)
        #pragma unroll
        for (int j = 0; j < 4; j++) {
            ag[i][j] = (f32x4){0.f, 0.f, 0.f, 0.f};
            au[i][j] = (f32x4){0.f, 0.f, 0.f, 0.f};
        }

    const unsigned short* Ab = xb  + ((size_t)gl * BT   + mt * 128) * DIN;
    const unsigned short* Gb = wgb + ((size_t)gl * DHID + ht * 128) * DIN;
    const unsigned short* Ub = wub + ((size_t)gl * DHID + ht * 128) * DIN;

    // staging geometry: 1024 slots of 16B per tile; wave w round r covers slots
    // (r*4+w)*64 + lane. Global chunk pre-swizzled: LDS[row][ch] <- global[row][ch^(row&7)]
    unsigned off[4]; int lb[4];
    #pragma unroll
    for (int r = 0; r < 4; r++) {
        int slot = (r * 4 + wave) * 64 + lane;
        int row = slot >> 3, ch = slot & 7;
        off[r] = (unsigned)row * DIN + (unsigned)(((ch ^ (row & 7)) * 8));
        lb[r]  = (r * 4 + wave) * 512;   // ushorts = 1024B
    }

    for (int k0 = 0; k0 < DIN; k0 += 64) {
        __syncthreads();
        #pragma unroll
        for (int r = 0; r < 4; r++) {
            async16(Ab + k0 + off[r], &As[lb[r]]);
            async16(Gb + k0 + off[r], &Bg[lb[r]]);
            async16(Ub + k0 + off[r], &Bu[lb[r]]);
        }
        __syncthreads();   // compiler emits vmcnt(0) drain: LDS writes landed
        #pragma unroll
        for (int kk = 0; kk < 2; kk++) {
            bf16x8 af[4], bgf[4], buf2[4];
            #pragma unroll
            for (int mi = 0; mi < 4; mi++) {
                int row = wm + mi * 16 + l16;
                int ch  = (kk * 4 + quad) ^ (row & 7);   // undo stage swizzle
                af[mi] = *(const bf16x8*)&As[row * 64 + ch * 8];
            }
            #pragma unroll
            for (int ni = 0; ni < 4; ni++) {
                int row = wn + ni * 16 + l16;
                int ch  = (kk * 4 + quad) ^ (row & 7);
                bgf[ni]  = *(const bf16x8*)&Bg[row * 64 + ch * 8];
                buf2[ni] = *(const bf16x8*)&Bu[row * 64 + ch * 8];
            }
            #pragma unroll
            for (int mi = 0; mi < 4; mi++)
                #pragma unroll
                for (int ni = 0; ni < 4; ni++) {
                    ag[mi][ni] = __builtin_amdgcn_mfma_f32_16x16x32_bf16(af[mi], bgf[ni],  ag[mi][ni], 0, 0, 0);
                    au[mi][ni] = __builtin_amdgcn_mfma_f32_16x16x32_bf16(af[mi], buf2[ni], au[mi][ni], 0, 0, 0);
                }
        }
    }

    unsigned short* hb = hid + (size_t)gl * BT * DHID;
    #pragma unroll
    for (int mi = 0; mi < 4; mi++)
        #pragma unroll
        for (int ni = 0; ni < 4; ni++)
            #pragma unroll
            for (int r = 0; r < 4; r++) {
                int row = mt * 128 + wm + mi * 16 + quad * 4 + r;
                int col = ht * 128 + wn + ni * 16 + l16;
                float gv = ag[mi][ni][r];
                float uv = au[mi][ni][r];
                float sv = gv / (1.f + __expf(-gv));
                hb[(size_t)row * DHID + col] = f2bf(sv * uv);
            }
}

// -------- GEMM 2: out = hidden @ Wd, fp32 out in token-interleaved rows --------
__global__ __launch_bounds__(256, 2)
void k_down(const unsigned short* __restrict__ hid,
            const unsigned short* __restrict__ wdb,
            float* __restrict__ out, int g0) {
    const int OT = DOUT / 128;   // 8
    const int MT = BT / 128;     // 32
    int bid = blockIdx.x;
    int ot = bid % OT;
    int mt = (bid / OT) % MT;
    int gl = bid / (OT * MT);
    int g  = g0 + gl;

    __shared__ unsigned short As[128 * 64];
    __shared__ unsigned short Bs[128 * 64];

    int tid = threadIdx.x;
    int lane = tid & 63, wave = tid >> 6;
    int quad = lane >> 4, l16 = lane & 15;
    int wm = (wave >> 1) * 64, wn = (wave & 1) * 64;

    f32x4 ac[4][4];
    #pragma unroll
    for (int i = 0; i < 4; i++)
        #pragma unroll
        for (int j = 0; j < 4; j++)
            ac[i][j] = (f32x4){0.f, 0.f, 0.f, 0.f};

    const unsigned short* Ab = hid + ((size_t)gl * BT   + mt * 128) * DHID;
    const unsigned short* Db = wdb + ((size_t)gl * DOUT + ot * 128) * DHID;

    unsigned off[4]; int lb[4];
    #pragma unroll
    for (int r = 0; r < 4; r++) {
        int slot = (r * 4 + wave) * 64 + lane;
        int row = slot >> 3, ch = slot & 7;
        off[r] = (unsigned)row * DHID + (unsigned)(((ch ^ (row & 7)) * 8));
        lb[r]  = (r * 4 + wave) * 512;
    }

    for (int k0 = 0; k0 < DHID; k0 += 64) {
        __syncthreads();
        #pragma unroll
        for (int r = 0; r < 4; r++) {
            async16(Ab + k0 + off[r], &As[lb[r]]);
            async16(Db + k0 + off[r], &Bs[lb[r]]);
        }
        __syncthreads();
        #pragma unroll
        for (int kk = 0; kk < 2; kk++) {
            bf16x8 af[4], bf[4];
            #pragma unroll
            for (int mi = 0; mi < 4; mi++) {
                int row = wm + mi * 16 + l16;
                int ch  = (kk * 4 + quad) ^ (row & 7);
                af[mi] = *(const bf16x8*)&As[row * 64 + ch * 8];
            }
            #pragma unroll
            for (int ni = 0; ni < 4; ni++) {
                int row = wn + ni * 16 + l16;
                int ch  = (kk * 4 + quad) ^ (row & 7);
                bf[ni] = *(const bf16x8*)&Bs[row * 64 + ch * 8];
            }
            #pragma unroll
            for (int mi = 0; mi < 4; mi++)
                #pragma unroll
                for (int ni = 0; ni < 4; ni++)
                    ac[mi][ni] = __builtin_amdgcn_mfma_f32_16x16x32_bf16(af[mi], bf[ni], ac[mi][ni], 0, 0, 0);
        }
    }

    #pragma unroll
    for (int mi = 0; mi < 4; mi++)
        #pragma unroll
        for (int ni = 0; ni < 4; ni++)
            #pragma unroll
            for (int r = 0; r < 4; r++) {
                int row = mt * 128 + wm + mi * 16 + quad * 4 + r;   // b_local
                int col = ot * 128 + wn + ni * 16 + l16;            // o
                out[((size_t)row * NG + g) * DOUT + col] = ac[mi][ni][r];
            }
}

extern "C" void kernel_launch(void* const* d_in, const int* in_sizes, int n_in,
                              void* d_out, int out_size, void* d_ws, size_t ws_size,
                              hipStream_t stream) {
    const float* x  = (const float*)d_in[0];
    const float* wg = (const float*)d_in[1];
    const float* wu = (const float*)d_in[2];
    const float* wd = (const float*)d_in[3];
    float* out = (float*)d_out;

    const size_t SZ_HID = (size_t)NG * BT * DHID * 2;   // 134 MB
    const size_t SZ_XB  = (size_t)NG * BT * DIN  * 2;   //  67 MB
    const size_t SZ_W   = (size_t)NG * DHID * DIN * 2;  //  33.5 MB each
    uint8_t* p = (uint8_t*)d_ws;

    if (ws_size >= SZ_HID + SZ_XB + 3 * SZ_W) {         // 288 MiB: full path
        unsigned short* hid = (unsigned short*)p;
        unsigned short* xb  = (unsigned short*)(p + SZ_HID);
        unsigned short* wgb = (unsigned short*)(p + SZ_HID + SZ_XB);
        unsigned short* wub = (unsigned short*)(p + SZ_HID + SZ_XB + SZ_W);
        unsigned short* wdb = (unsigned short*)(p + SZ_HID + SZ_XB + 2 * SZ_W);
        k_cvt_x<<<2048, 256, 0, stream>>>(x, xb, 0, NG);
        k_cvt_wT<<<dim3(DHID / 64, DIN / 64, NG), 256, 0, stream>>>(wg, wgb, DIN, DHID, 0);
        k_cvt_wT<<<dim3(DHID / 64, DIN / 64, NG), 256, 0, stream>>>(wu, wub, DIN, DHID, 0);
        k_cvt_wT<<<dim3(DOUT / 64, DHID / 64, NG), 256, 0, stream>>>(wd, wdb, DHID, DOUT, 0);
        k_gateup<<<NG * (BT / 128) * (DHID / 128), 256, 0, stream>>>(xb, wgb, wub, hid);
        k_down  <<<NG * (BT / 128) * (DOUT / 128), 256, 0, stream>>>(hid, wdb, out, 0);
    } else {                                            // per-group fallback: 36 MiB
        const size_t zh = SZ_HID / NG, zx = SZ_XB / NG, zw = SZ_W / NG;
        unsigned short* hid = (unsigned short*)p;
        unsigned short* xb  = (unsigned short*)(p + zh);
        unsigned short* wgb = (unsigned short*)(p + zh + zx);
        unsigned short* wub = (unsigned short*)(p + zh + zx + zw);
        unsigned short* wdb = (unsigned short*)(p + zh + zx + 2 * zw);
        for (int g = 0; g < NG; g++) {
            k_cvt_x<<<1024, 256, 0, stream>>>(x, xb, g, 1);
            k_cvt_wT<<<dim3(DHID / 64, DIN / 64, 1), 256, 0, stream>>>(wg, wgb, DIN, DHID, g);
            k_cvt_wT<<<dim3(DHID / 64, DIN / 64, 1), 256, 0, stream>>>(wu, wub, DIN, DHID, g);
            k_cvt_wT<<<dim3(DOUT / 64, DHID / 64, 1), 256, 0, stream>>>(wd, wdb, DHID, DOUT, g);
            k_gateup<<<(BT / 128) * (DHID / 128), 256, 0, stream>>>(xb, wgb, wub, hid);
            k_down  <<<(BT / 128) * (DOUT / 128), 256, 0, stream>>>(hid, wdb, out, g);
        }
    }
}

// Round 2
// 812.813 us; speedup vs baseline: 1.2626x; 1.0195x over previous
//
#include <hip/hip_runtime.h>
#include <stdint.h>

#define NG   8
#define BT   4096
#define DIN  1024
#define DHID 2048
#define DOUT 1024

typedef __bf16 bf16x8 __attribute__((ext_vector_type(8)));
typedef float  f32x4  __attribute__((ext_vector_type(4)));

__device__ __forceinline__ unsigned short f2bf(float f) {
    union { float f; unsigned u; } v; v.f = f;
    // round-to-nearest-even fp32 -> bf16
    return (unsigned short)((v.u + 0x7fffu + ((v.u >> 16) & 1u)) >> 16);
}

// async 16B global -> LDS. LDS dest: wave-uniform base + lane*16 (HW). Global src per-lane.
__device__ __forceinline__ void async16(const unsigned short* g, unsigned short* l) {
    __builtin_amdgcn_global_load_lds((const __attribute__((address_space(1))) void*)g,
                                     (__attribute__((address_space(3))) void*)l,
                                     16, 0, 0);
}

// ---------------- prepass 1: x (fp32, token-interleaved) -> xb[gl][b][k] bf16 ----------------
__global__ __launch_bounds__(256)
void k_cvt_x(const float* __restrict__ x, unsigned short* __restrict__ xb,
             int g0, int ngl) {
    size_t total = (size_t)ngl * BT * (DIN / 4);
    size_t stride = (size_t)gridDim.x * blockDim.x;
    for (size_t i = (size_t)blockIdx.x * blockDim.x + threadIdx.x; i < total; i += stride) {
        size_t e = i * 4;
        int k  = (int)(e & (DIN - 1));
        size_t rb = e >> 10;
        int b  = (int)(rb & (BT - 1));
        int gl = (int)(rb >> 12);
        const float4 v = *(const float4*)(x + ((size_t)b * NG + (g0 + gl)) * DIN + k);
        ushort4 h;
        h.x = f2bf(v.x); h.y = f2bf(v.y); h.z = f2bf(v.z); h.w = f2bf(v.w);
        *(ushort4*)(xb + e) = h;
    }
}

// ---------------- prepass 2: weight [g][K][N] fp32 -> [gl][N][K] bf16 ----------------
__global__ __launch_bounds__(256)
void k_cvt_wT(const float* __restrict__ w, unsigned short* __restrict__ wt,
              int K, int N, int g0) {
    __shared__ unsigned short ts[64][72];
    int nt = blockIdx.x;
    int kt = blockIdx.y;
    int gl = blockIdx.z;
    const float* src = w + ((size_t)(g0 + gl) * K + kt * 64) * N + nt * 64;
    unsigned short* dst = wt + ((size_t)gl * N + nt * 64) * K + kt * 64;
    int tid = threadIdx.x;
    int c4 = (tid & 15) * 4;
    int r0 = tid >> 4;
    #pragma unroll
    for (int i = 0; i < 4; i++) {
        int r = r0 + i * 16;
        float4 v = *(const float4*)(src + (size_t)r * N + c4);
        ts[c4 + 0][r] = f2bf(v.x);
        ts[c4 + 1][r] = f2bf(v.y);
        ts[c4 + 2][r] = f2bf(v.z);
        ts[c4 + 3][r] = f2bf(v.w);
    }
    __syncthreads();
    int kc = (tid & 7) * 8;
    int n0 = tid >> 3;
    #pragma unroll
    for (int i = 0; i < 2; i++) {
        int n = n0 + i * 32;
        uint4 v = *(const uint4*)&ts[n][kc];
        *(uint4*)(dst + (size_t)n * K + kc) = v;
    }
}

// -------- GEMM 1 (8-phase): hid[gl][b][h] = silu(x@Wg)*(x@Wu), BM=256 BN=128(dual) BK=64 --------
__global__ __launch_bounds__(512, 2)
void k_gateup(const unsigned short* __restrict__ xb,
              const unsigned short* __restrict__ wgb,
              const unsigned short* __restrict__ wub,
              unsigned short* __restrict__ hid) {
    // grid: ht(16) fastest, mt(16), gl ; XCD-bijective swizzle (grid % 8 == 0 both paths)
    int cpx = gridDim.x >> 3;
    int bid = (blockIdx.x & 7) * cpx + (blockIdx.x >> 3);
    int ht = bid & 15;
    int mt = (bid >> 4) & 15;
    int gl = bid >> 8;

    __shared__ unsigned short As[2][256 * 64];   // 64 KiB
    __shared__ unsigned short Bg[2][128 * 64];   // 32 KiB
    __shared__ unsigned short Bu[2][128 * 64];   // 32 KiB

    int tid  = threadIdx.x;
    int lane = tid & 63, wave = tid >> 6;
    int quad = lane >> 4, l16 = lane & 15;
    int wm = (wave >> 1) * 64;   // 4 M-waves
    int wn = (wave & 1) * 64;    // 2 N-waves

    f32x4 ag[4][4], au[4][4];
    #pragma unroll
    for (int i = 0; i < 4; i++)
        #pragma unroll
        for (int j = 0; j < 4; j++) {
            ag[i][j] = (f32x4){0.f, 0.f, 0.f, 0.f};
            au[i][j] = (f32x4){0.f, 0.f, 0.f, 0.f};
        }

    const unsigned short* Ab = xb  + ((size_t)gl * BT   + mt * 256) * DIN;
    const unsigned short* Gb = wgb + ((size_t)gl * DHID + ht * 128) * DIN;
    const unsigned short* Ub = wub + ((size_t)gl * DHID + ht * 128) * DIN;

    // staging: slot = (r*8+wave)*64+lane ; row=slot>>3, ch=slot&7 ; content chunk-XOR swizzled
    unsigned off[4]; int lb[4];
    #pragma unroll
    for (int r = 0; r < 4; r++) {
        int slot = (r * 8 + wave) * 64 + lane;
        int row = slot >> 3, ch = slot & 7;
        off[r] = (unsigned)row * DIN + (unsigned)((ch ^ (row & 7)) * 8);
        lb[r]  = (r * 8 + wave) * 512;
    }

    // prologue: stage K-tile 0 into buffer 0
    #pragma unroll
    for (int r = 0; r < 4; r++) async16(Ab + off[r], &As[0][lb[r]]);
    #pragma unroll
    for (int r = 0; r < 2; r++) {
        async16(Gb + off[r], &Bg[0][lb[r]]);
        async16(Ub + off[r], &Bu[0][lb[r]]);
    }
    __syncthreads();

    int cur = 0;
    const int NT = DIN / 64;   // 16
    for (int t = 0; t < NT; ++t) {
        const unsigned kn = (unsigned)(t + 1) * 64;
        const bool pf = (t + 1 < NT);
        bf16x8 af[4], bg[4], bu[4];

        // ---- phase 0: gate, kk=0 ----
        #pragma unroll
        for (int mi = 0; mi < 4; mi++) {
            int row = wm + mi * 16 + l16;
            int ch  = quad ^ (row & 7);
            af[mi] = *(const bf16x8*)&As[cur][row * 64 + ch * 8];
        }
        #pragma unroll
        for (int ni = 0; ni < 4; ni++) {
            int row = wn + ni * 16 + l16;
            int ch  = quad ^ (row & 7);
            bg[ni] = *(const bf16x8*)&Bg[cur][row * 64 + ch * 8];
        }
        if (pf) {
            #pragma unroll
            for (int r = 0; r < 4; r++) async16(Ab + kn + off[r], &As[cur ^ 1][lb[r]]);
        }
        __builtin_amdgcn_s_barrier();
        __builtin_amdgcn_s_setprio(1);
        #pragma unroll
        for (int mi = 0; mi < 4; mi++)
            #pragma unroll
            for (int ni = 0; ni < 4; ni++)
                ag[mi][ni] = __builtin_amdgcn_mfma_f32_16x16x32_bf16(af[mi], bg[ni], ag[mi][ni], 0, 0, 0);
        __builtin_amdgcn_s_setprio(0);
        __builtin_amdgcn_s_barrier();

        // ---- phase 1: up, kk=0 (reuse af) ----
        #pragma unroll
        for (int ni = 0; ni < 4; ni++) {
            int row = wn + ni * 16 + l16;
            int ch  = quad ^ (row & 7);
            bu[ni] = *(const bf16x8*)&Bu[cur][row * 64 + ch * 8];
        }
        if (pf) {
            #pragma unroll
            for (int r = 0; r < 2; r++) {
                async16(Gb + kn + off[r], &Bg[cur ^ 1][lb[r]]);
                async16(Ub + kn + off[r], &Bu[cur ^ 1][lb[r]]);
            }
        }
        __builtin_amdgcn_s_barrier();
        __builtin_amdgcn_s_setprio(1);
        #pragma unroll
        for (int mi = 0; mi < 4; mi++)
            #pragma unroll
            for (int ni = 0; ni < 4; ni++)
                au[mi][ni] = __builtin_amdgcn_mfma_f32_16x16x32_bf16(af[mi], bu[ni], au[mi][ni], 0, 0, 0);
        __builtin_amdgcn_s_setprio(0);
        __builtin_amdgcn_s_barrier();

        // ---- phase 2: gate, kk=1 ----
        #pragma unroll
        for (int mi = 0; mi < 4; mi++) {
            int row = wm + mi * 16 + l16;
            int ch  = (4 + quad) ^ (row & 7);
            af[mi] = *(const bf16x8*)&As[cur][row * 64 + ch * 8];
        }
        #pragma unroll
        for (int ni = 0; ni < 4; ni++) {
            int row = wn + ni * 16 + l16;
            int ch  = (4 + quad) ^ (row & 7);
            bg[ni] = *(const bf16x8*)&Bg[cur][row * 64 + ch * 8];
        }
        __builtin_amdgcn_s_barrier();
        __builtin_amdgcn_s_setprio(1);
        #pragma unroll
        for (int mi = 0; mi < 4; mi++)
            #pragma unroll
            for (int ni = 0; ni < 4; ni++)
                ag[mi][ni] = __builtin_amdgcn_mfma_f32_16x16x32_bf16(af[mi], bg[ni], ag[mi][ni], 0, 0, 0);
        __builtin_amdgcn_s_setprio(0);
        __builtin_amdgcn_s_barrier();

        // ---- phase 3: up, kk=1 ----
        #pragma unroll
        for (int ni = 0; ni < 4; ni++) {
            int row = wn + ni * 16 + l16;
            int ch  = (4 + quad) ^ (row & 7);
            bu[ni] = *(const bf16x8*)&Bu[cur][row * 64 + ch * 8];
        }
        __builtin_amdgcn_s_barrier();
        __builtin_amdgcn_s_setprio(1);
        #pragma unroll
        for (int mi = 0; mi < 4; mi++)
            #pragma unroll
            for (int ni = 0; ni < 4; ni++)
                au[mi][ni] = __builtin_amdgcn_mfma_f32_16x16x32_bf16(af[mi], bu[ni], au[mi][ni], 0, 0, 0);
        __builtin_amdgcn_s_setprio(0);
        __syncthreads();   // tile boundary: drains vmcnt(0) -> prefetched tile ready
        cur ^= 1;
    }

    // ---- epilogue: silu(gate)*up -> bf16 ----
    unsigned short* hb = hid + (size_t)gl * BT * DHID;
    #pragma unroll
    for (int mi = 0; mi < 4; mi++)
        #pragma unroll
        for (int ni = 0; ni < 4; ni++)
            #pragma unroll
            for (int r = 0; r < 4; r++) {
                int row = mt * 256 + wm + mi * 16 + quad * 4 + r;
                int col = ht * 128 + wn + ni * 16 + l16;
                float gv = ag[mi][ni][r];
                float uv = au[mi][ni][r];
                float sv = gv / (1.f + __expf(-gv));
                hb[(size_t)row * DHID + col] = f2bf(sv * uv);
            }
}

// -------- GEMM 2 (8-phase): out = hidden @ Wd, BM=256 BN=256 BK=64 --------
__global__ __launch_bounds__(512, 2)
void k_down(const unsigned short* __restrict__ hid,
            const unsigned short* __restrict__ wdb,
            float* __restrict__ out, int g0) {
    int cpx = gridDim.x >> 3;
    int bid = (blockIdx.x & 7) * cpx + (blockIdx.x >> 3);
    int ot = bid & 3;
    int mt = (bid >> 2) & 15;
    int gl = bid >> 6;
    int g  = g0 + gl;

    __shared__ unsigned short As[2][256 * 64];   // 64 KiB
    __shared__ unsigned short Bs[2][256 * 64];   // 64 KiB

    int tid  = threadIdx.x;
    int lane = tid & 63, wave = tid >> 6;
    int quad = lane >> 4, l16 = lane & 15;
    int wm = (wave >> 2) * 128;   // 2 M-waves
    int wn = (wave & 3) * 64;     // 4 N-waves

    f32x4 ac[8][4];
    #pragma unroll
    for (int i = 0; i < 8; i++)
        #pragma unroll
        for (int j = 0; j < 4; j++)
            ac[i][j] = (f32x4){0.f, 0.f, 0.f, 0.f};

    const unsigned short* Ab = hid + ((size_t)gl * BT   + mt * 256) * DHID;
    const unsigned short* Db = wdb + ((size_t)gl * DOUT + ot * 256) * DHID;

    unsigned off[4]; int lb[4];
    #pragma unroll
    for (int r = 0; r < 4; r++) {
        int slot = (r * 8 + wave) * 64 + lane;
        int row = slot >> 3, ch = slot & 7;
        off[r] = (unsigned)row * DHID + (unsigned)((ch ^ (row & 7)) * 8);
        lb[r]  = (r * 8 + wave) * 512;
    }

    #pragma unroll
    for (int r = 0; r < 4; r++) {
        async16(Ab + off[r], &As[0][lb[r]]);
        async16(Db + off[r], &Bs[0][lb[r]]);
    }
    __syncthreads();

    int cur = 0;
    const int NT = DHID / 64;   // 32
    for (int t = 0; t < NT; ++t) {
        const unsigned kn = (unsigned)(t + 1) * 64;
        const bool pf = (t + 1 < NT);
        bf16x8 af[4], bf[4];

        // ---- phase 0: M-half 0, kk=0 ----
        #pragma unroll
        for (int mi = 0; mi < 4; mi++) {
            int row = wm + mi * 16 + l16;
            int ch  = quad ^ (row & 7);
            af[mi] = *(const bf16x8*)&As[cur][row * 64 + ch * 8];
        }
        #pragma unroll
        for (int ni = 0; ni < 4; ni++) {
            int row = wn + ni * 16 + l16;
            int ch  = quad ^ (row & 7);
            bf[ni] = *(const bf16x8*)&Bs[cur][row * 64 + ch * 8];
        }
        if (pf) {
            #pragma unroll
            for (int r = 0; r < 4; r++) async16(Ab + kn + off[r], &As[cur ^ 1][lb[r]]);
        }
        __builtin_amdgcn_s_barrier();
        __builtin_amdgcn_s_setprio(1);
        #pragma unroll
        for (int mi = 0; mi < 4; mi++)
            #pragma unroll
            for (int ni = 0; ni < 4; ni++)
                ac[mi][ni] = __builtin_amdgcn_mfma_f32_16x16x32_bf16(af[mi], bf[ni], ac[mi][ni], 0, 0, 0);
        __builtin_amdgcn_s_setprio(0);
        __builtin_amdgcn_s_barrier();

        // ---- phase 1: M-half 1, kk=0 (reuse bf) ----
        #pragma unroll
        for (int mi = 0; mi < 4; mi++) {
            int row = wm + 64 + mi * 16 + l16;
            int ch  = quad ^ (row & 7);
            af[mi] = *(const bf16x8*)&As[cur][row * 64 + ch * 8];
        }
        if (pf) {
            #pragma unroll
            for (int r = 0; r < 4; r++) async16(Db + kn + off[r], &Bs[cur ^ 1][lb[r]]);
        }
        __builtin_amdgcn_s_barrier();
        __builtin_amdgcn_s_setprio(1);
        #pragma unroll
        for (int mi = 0; mi < 4; mi++)
            #pragma unroll
            for (int ni = 0; ni < 4; ni++)
                ac[4 + mi][ni] = __builtin_amdgcn_mfma_f32_16x16x32_bf16(af[mi], bf[ni], ac[4 + mi][ni], 0, 0, 0);
        __builtin_amdgcn_s_setprio(0);
        __builtin_amdgcn_s_barrier();

        // ---- phase 2: M-half 0, kk=1 ----
        #pragma unroll
        for (int mi = 0; mi < 4; mi++) {
            int row = wm + mi * 16 + l16;
            int ch  = (4 + quad) ^ (row & 7);
            af[mi] = *(const bf16x8*)&As[cur][row * 64 + ch * 8];
        }
        #pragma unroll
        for (int ni = 0; ni < 4; ni++) {
            int row = wn + ni * 16 + l16;
            int ch  = (4 + quad) ^ (row & 7);
            bf[ni] = *(const bf16x8*)&Bs[cur][row * 64 + ch * 8];
        }
        __builtin_amdgcn_s_barrier();
        __builtin_amdgcn_s_setprio(1);
        #pragma unroll
        for (int mi = 0; mi < 4; mi++)
            #pragma unroll
            for (int ni = 0; ni < 4; ni++)
                ac[mi][ni] = __builtin_amdgcn_mfma_f32_16x16x32_bf16(af[mi], bf[ni], ac[mi][ni], 0, 0, 0);
        __builtin_amdgcn_s_setprio(0);
        __builtin_amdgcn_s_barrier();

        // ---- phase 3: M-half 1, kk=1 ----
        #pragma unroll
        for (int mi = 0; mi < 4; mi++) {
            int row = wm + 64 + mi * 16 + l16;
            int ch  = (4 + quad) ^ (row & 7);
            af[mi] = *(const bf16x8*)&As[cur][row * 64 + ch * 8];
        }
        __builtin_amdgcn_s_barrier();
        __builtin_amdgcn_s_setprio(1);
        #pragma unroll
        for (int mi = 0; mi < 4; mi++)
            #pragma unroll
            for (int ni = 0; ni < 4; ni++)
                ac[4 + mi][ni] = __builtin_amdgcn_mfma_f32_16x16x32_bf16(af[mi], bf[ni], ac[4 + mi][ni], 0, 0, 0);
        __builtin_amdgcn_s_setprio(0);
        __syncthreads();
        cur ^= 1;
    }

    #pragma unroll
    for (int mi = 0; mi < 8; mi++)
        #pragma unroll
        for (int ni = 0; ni < 4; ni++)
            #pragma unroll
            for (int r = 0; r < 4; r++) {
                int row = mt * 256 + wm + mi * 16 + quad * 4 + r;   // b_local
                int col = ot * 256 + wn + ni * 16 + l16;            // o
                out[((size_t)row * NG + g) * DOUT + col] = ac[mi][ni][r];
            }
}

extern "C" void kernel_launch(void* const* d_in, const int* in_sizes, int n_in,
                              void* d_out, int out_size, void* d_ws, size_t ws_size,
                              hipStream_t stream) {
    const float* x  = (const float*)d_in[0];
    const float* wg = (const float*)d_in[1];
    const float* wu = (const float*)d_in[2];
    const float* wd = (const float*)d_in[3];
    float* out = (float*)d_out;

    const size_t SZ_HID = (size_t)NG * BT * DHID * 2;
    const size_t SZ_XB  = (size_t)NG * BT * DIN  * 2;
    const size_t SZ_W   = (size_t)NG * DHID * DIN * 2;
    uint8_t* p = (uint8_t*)d_ws;

    if (ws_size >= SZ_HID + SZ_XB + 3 * SZ_W) {
        unsigned short* hid = (unsigned short*)p;
        unsigned short* xb  = (unsigned short*)(p + SZ_HID);
        unsigned short* wgb = (unsigned short*)(p + SZ_HID + SZ_XB);
        unsigned short* wub = (unsigned short*)(p + SZ_HID + SZ_XB + SZ_W);
        unsigned short* wdb = (unsigned short*)(p + SZ_HID + SZ_XB + 2 * SZ_W);
        k_cvt_x<<<2048, 256, 0, stream>>>(x, xb, 0, NG);
        k_cvt_wT<<<dim3(DHID / 64, DIN / 64, NG), 256, 0, stream>>>(wg, wgb, DIN, DHID, 0);
        k_cvt_wT<<<dim3(DHID / 64, DIN / 64, NG), 256, 0, stream>>>(wu, wub, DIN, DHID, 0);
        k_cvt_wT<<<dim3(DOUT / 64, DHID / 64, NG), 256, 0, stream>>>(wd, wdb, DHID, DOUT, 0);
        k_gateup<<<NG * (BT / 256) * (DHID / 128), 512, 0, stream>>>(xb, wgb, wub, hid);
        k_down  <<<NG * (BT / 256) * (DOUT / 256), 512, 0, stream>>>(hid, wdb, out, 0);
    } else {
        const size_t zh = SZ_HID / NG, zx = SZ_XB / NG, zw = SZ_W / NG;
        unsigned short* hid = (unsigned short*)p;
        unsigned short* xb  = (unsigned short*)(p + zh);
        unsigned short* wgb = (unsigned short*)(p + zh + zx);
        unsigned short* wub = (unsigned short*)(p + zh + zx + zw);
        unsigned short* wdb = (unsigned short*)(p + zh + zx + 2 * zw);
        for (int g = 0; g < NG; g++) {
            k_cvt_x<<<1024, 256, 0, stream>>>(x, xb, g, 1);
            k_cvt_wT<<<dim3(DHID / 64, DIN / 64, 1), 256, 0, stream>>>(wg, wgb, DIN, DHID, g);
            k_cvt_wT<<<dim3(DHID / 64, DIN / 64, 1), 256, 0, stream>>>(wu, wub, DIN, DHID, g);
            k_cvt_wT<<<dim3(DOUT / 64, DHID / 64, 1), 256, 0, stream>>>(wd, wdb, DHID, DOUT, g);
            k_gateup<<<(BT / 256) * (DHID / 128), 512, 0, stream>>>(xb, wgb, wub, hid);
            k_down  <<<(BT / 256) * (DOUT / 256), 512, 0, stream>>>(hid, wdb, out, g);
        }
    }
}